// Round 17
// baseline (61.801 us; speedup 1.0000x reference)
//
#include <hip/hip_runtime.h>
#include <hip/hip_bf16.h>
#include <stdint.h>

typedef unsigned short u16;
typedef unsigned int   u32;
typedef unsigned long long u64;

#define N_ROWS 4096
#define DIM    512
#define NT32   128         // N_ROWS / 32 tiles per side
#define NPAIR32 8256       // NT32*(NT32+1)/2 (= 8 * 1032)
#define MOD3   729         // 3^6
#define NLEV   6           // levels v = 0..5
#define NKS    16          // DIM / 32 k-steps
#define NSLOT  64          // accumulator replication (de-contended atomics)
#define PDEPTH 6           // register pipeline sets (prefetch distance 5)

typedef __attribute__((ext_vector_type(4))) float f32x4;

// ---- workspace layout (byte offsets) ----
// zpack: fragment-packed FP8 e4m3, FLAT layout (PROVEN R8/R9/R16, absmax 0):
// block (R, s) for 16-row group R, k-step s (32 k) is 512 B at ((R<<4)+s)*512;
// lane L's 8 B at u64 slot L.  Byte addr = R*8192 + s*512 + lane*8.
#define WS_ZPK 0
#define WS_SQ  (N_ROWS * DIM)
#define WS_R   (WS_SQ + N_ROWS * 4)
#define WS_ACC (WS_R + N_ROWS * 4)          // float gsum2[64][8]; u32 gcnt2[64][8]

// ---------------------------------------------------------------------------
// Prep (R8/R9/R16 verbatim, PROVEN): f32 -> fp8 pack into flat zpack, row
// sum-of-squares, idx % 729; row 0 zeroes the 64-slot accumulators.
// ---------------------------------------------------------------------------
__global__ __launch_bounds__(256)
void prep_kernel(const float* __restrict__ z, const int* __restrict__ idx,
                 u64* __restrict__ zpack, float* __restrict__ sq,
                 int* __restrict__ rres, u32* __restrict__ acczero)
{
    const int lane = threadIdx.x & 63;
    const int row  = blockIdx.x * 4 + (threadIdx.x >> 6);
    const float4* zr = reinterpret_cast<const float4*>(z + (size_t)row * DIM) + lane * 2;
    float4 v0 = zr[0], v1 = zr[1];
    float f[8] = {v0.x, v0.y, v0.z, v0.w, v1.x, v1.y, v1.z, v1.w};
    float ss = 0.f;
#pragma unroll
    for (int k = 0; k < 8; ++k) ss += f[k] * f[k];
    int lo = __builtin_amdgcn_cvt_pk_fp8_f32(f[0], f[1], 0, false);
    lo     = __builtin_amdgcn_cvt_pk_fp8_f32(f[2], f[3], lo, true);
    int hi = __builtin_amdgcn_cvt_pk_fp8_f32(f[4], f[5], 0, false);
    hi     = __builtin_amdgcn_cvt_pk_fp8_f32(f[6], f[7], hi, true);
    const u64 pk = (u64)(u32)lo | ((u64)(u32)hi << 32);
    zpack[((size_t)((row >> 4) * 16 + (lane >> 2)) << 6)
          + (lane & 3) * 16 + (row & 15)] = pk;
#pragma unroll
    for (int off = 32; off > 0; off >>= 1) ss += __shfl_down(ss, off, 64);
    if (lane == 0) {
        sq[row] = ss;
        rres[row] = idx[row] % MOD3;   // idx >= 0
    }
    if (row == 0) {
#pragma unroll
        for (int i = 0; i < 16; ++i) acczero[lane + i * 64] = 0u;
    }
}

// ---------------------------------------------------------------------------
// Epilogue (R9/R16 verbatim, PROVEN absmax 0; 2x2 fragment grid).
// ---------------------------------------------------------------------------
template<bool DIAG>
__device__ __forceinline__ void epilogue_acc(
    const f32x4 (&acc)[2][2], const float* sqI, const float* sqJ,
    const int* rI, const int* rJ, int lane,
    float (&lsum)[NLEV], u64& pcnt)
{
    const int rbase = (lane >> 4) * 4;   // C/D: row=(lane>>4)*4+q, col=lane&15
    const int cbase = lane & 15;
#pragma unroll
    for (int m = 0; m < 2; ++m) {
        const int il0 = m * 16 + rbase;
#pragma unroll
        for (int n = 0; n < 2; ++n) {
            const int jl  = n * 16 + cbase;
            const float sqj = sqJ[jl];
            const int   rj  = rJ[jl];
#pragma unroll
            for (int q = 0; q < 4; ++q) {
                const int il = il0 + q;
                float d2 = fmaxf(sqI[il] + sqj - 2.0f * acc[m][n][q], 0.f);
                const float dist = __builtin_amdgcn_sqrtf(d2);
                int dm = rI[il] - rj;
                dm += (dm >> 31) & MOD3;            // mod 729 into [0,729)
                const u32 x = (u32)dm;
                int v =
                    (x * 2863311531u <= 1431655765u) +   // 3
                    (x *  954437177u <=  477218588u) +   // 9
                    (x * 1749801491u <=  159072862u) +   // 27
                    (x * 2014922929u <=   53024287u) +   // 81
                    (x * 3534952507u <=   17674762u) +   // 243
                    (x * 4041629033u <=    5891587u);    // 729 (x==0 -> 6)
                if (DIAG) {
                    v = (jl > il) ? v : 6;    // same tile: local upper-tri only
                }
                float tv = 1.0f;
                tv = (v == 1) ? (1.f / 3.f)   : tv;
                tv = (v == 2) ? (1.f / 9.f)   : tv;
                tv = (v == 3) ? (1.f / 27.f)  : tv;
                tv = (v == 4) ? (1.f / 81.f)  : tv;
                tv = (v == 5) ? (1.f / 243.f) : tv;
                const float dd  = dist - tv;
                const float sqd = dd * dd;
#pragma unroll
                for (int vv = 0; vv < NLEV; ++vv)
                    lsum[vv] += (v == vv) ? sqd : 0.f;
                pcnt += 1ull << (8 * v);            // 8-bit field per class (<=16)
            }
        }
    }
}

// ---------------------------------------------------------------------------
// Main: ONE WAVE per block, one 32x32 tile pair (ti <= tj), fp8 operands.
// INLINE-ASM register pipeline: global_load_dwordx2 via asm volatile with
// "=&v" outputs -- the scheduler CANNOT sink them and the allocator MUST
// keep all 6 sets (48 VGPR) live from def to MFMA use. Explicit counted
// s_waitcnt vmcnt(N) (4 loads/set; set s done when outstanding <= 4*(sets
// issued after s)) + sched_barrier(0) fence after each wait (rule #18:
// MFMAs otherwise hoist past asm waitcnt). SGPR-base + shared voffset
// addressing (voff = lane*8 + s*512). 8256 blocks x <=128 VGPR -> 4
// waves/SIMD: TLP x held-ILP for the first time.
// ---------------------------------------------------------------------------
__global__ __launch_bounds__(64, 4)
void pair_kernel(const u64* __restrict__ zpack, const float* __restrict__ sq,
                 const int* __restrict__ rres, float* __restrict__ gsum2,
                 u32* __restrict__ gcnt2)
{
    __shared__ float sqI[32], sqJ[32];
    __shared__ int   rI[32], rJ[32];

    const int lane = threadIdx.x;

    // bijective XCD swizzle (8256 = 8 * 1032)
    const int wg = (blockIdx.x & 7) * (NPAIR32 / 8) + (blockIdx.x >> 3);
    int t = wg, ti = 0, rem = NT32;
    while (t >= rem) { t -= rem; ++ti; --rem; }
    const int tj = ti + t;
    const int I0 = ti * 32, J0 = tj * 32;

    // aux staging: plain loads + LDS writes (compiler-managed waits), fully
    // fenced BEFORE the asm k-loop so its vmcnt queue holds only frag loads.
    if (lane < 32) {
        sqI[lane] = sq[I0 + lane];
        rI[lane]  = rres[I0 + lane];
    } else {
        const int s = lane - 32;
        sqJ[s] = sq[J0 + s];
        rJ[s]  = rres[J0 + s];
    }
    __builtin_amdgcn_sched_barrier(0);

    const int RA = 2 * ti, RB = 2 * tj;   // 16-row group bases
    const u64* bA0 = zpack + ((size_t)RA << 10);        // R*8192 bytes
    const u64* bA1 = zpack + ((size_t)(RA + 1) << 10);
    const u64* bB0 = zpack + ((size_t)RB << 10);
    const u64* bB1 = zpack + ((size_t)(RB + 1) << 10);
    const u32 lane8 = (u32)lane * 8u;

    f32x4 acc[2][2];
#pragma unroll
    for (int m = 0; m < 2; ++m)
#pragma unroll
        for (int n = 0; n < 2; ++n) acc[m][n] = (f32x4){0.f, 0.f, 0.f, 0.f};

    long A[PDEPTH][2], B[PDEPTH][2];

#define LOADF(d, s)                                                            \
    {                                                                          \
        const u32 voff = lane8 + (u32)((s) * 512);                             \
        asm volatile("global_load_dwordx2 %0, %1, %2"                          \
                     : "=&v"(A[d][0]) : "v"(voff), "s"(bA0) : "memory");       \
        asm volatile("global_load_dwordx2 %0, %1, %2"                          \
                     : "=&v"(A[d][1]) : "v"(voff), "s"(bA1) : "memory");       \
        asm volatile("global_load_dwordx2 %0, %1, %2"                          \
                     : "=&v"(B[d][0]) : "v"(voff), "s"(bB0) : "memory");       \
        asm volatile("global_load_dwordx2 %0, %1, %2"                          \
                     : "=&v"(B[d][1]) : "v"(voff), "s"(bB1) : "memory");       \
    }
#define MFMA_ALL(d)                                                            \
    {                                                                          \
        _Pragma("unroll")                                                      \
        for (int m = 0; m < 2; ++m)                                            \
            _Pragma("unroll")                                                  \
            for (int n = 0; n < 2; ++n)                                        \
                acc[m][n] = __builtin_amdgcn_mfma_f32_16x16x32_fp8_fp8(        \
                    A[d][m], B[d][n], acc[d ? m : m][n], 0, 0, 0);             \
    }

    // prologue: fill 5 of 6 sets (20 loads in flight)
    LOADF(0, 0); LOADF(1, 1); LOADF(2, 2); LOADF(3, 3); LOADF(4, 4);
    // steady state (fully unrolled; all indices + waitcnts compile-time):
#pragma unroll
    for (int s = 0; s < NKS; ++s) {
        if (s + 5 < NKS) LOADF((s + 5) % PDEPTH, s + 5);
        // set s complete <=> outstanding <= 4 * (#sets issued after s)
        if (s <= 10)      asm volatile("s_waitcnt vmcnt(20)" ::: "memory");
        else if (s == 11) asm volatile("s_waitcnt vmcnt(16)" ::: "memory");
        else if (s == 12) asm volatile("s_waitcnt vmcnt(12)" ::: "memory");
        else if (s == 13) asm volatile("s_waitcnt vmcnt(8)"  ::: "memory");
        else if (s == 14) asm volatile("s_waitcnt vmcnt(4)"  ::: "memory");
        else              asm volatile("s_waitcnt vmcnt(0)"  ::: "memory");
        __builtin_amdgcn_sched_barrier(0);   // rule #18: fence MFMA hoisting
        {
            const int d = s % PDEPTH;
#pragma unroll
            for (int m = 0; m < 2; ++m)
#pragma unroll
                for (int n = 0; n < 2; ++n)
                    acc[m][n] = __builtin_amdgcn_mfma_f32_16x16x32_fp8_fp8(
                        A[d][m], B[d][n], acc[m][n], 0, 0, 0);
        }
    }
#undef LOADF
#undef MFMA_ALL

    // ---- fused epilogue (1 wave: no barriers anywhere) ----
    float lsum[NLEV] = {0.f, 0.f, 0.f, 0.f, 0.f, 0.f};
    u64 pcnt = 0ull;
    if (ti == tj) epilogue_acc<true >(acc, sqI, sqJ, rI, rJ, lane, lsum, pcnt);
    else          epilogue_acc<false>(acc, sqI, sqJ, rI, rJ, lane, lsum, pcnt);

    // wave shuffle reduce, then atomics into slot (blockIdx & 63)
    const int slot = (int)(blockIdx.x & (NSLOT - 1));
#pragma unroll
    for (int vv = 0; vv < NLEV; ++vv) {
        float s = lsum[vv];
        u32   c = (u32)((pcnt >> (8 * vv)) & 255ull);
#pragma unroll
        for (int off = 32; off > 0; off >>= 1) {
            s += __shfl_xor(s, off, 64);
            c += __shfl_xor(c, off, 64);
        }
        if (lane == 0) {
            atomicAdd(&gsum2[slot * 8 + vv], s);
            atomicAdd(&gcnt2[slot * 8 + vv], c);
        }
    }
}

// ---------------------------------------------------------------------------
// Finalize (verbatim): lane t owns slot t; shuffle-reduce the 64 slots.
// ---------------------------------------------------------------------------
__global__ __launch_bounds__(64)
void finalize_kernel(const float* __restrict__ gsum2,
                     const u32* __restrict__ gcnt2,
                     float* __restrict__ out)
{
    const int lane = threadIdx.x;
    float s[NLEV];
    u32   c[NLEV];
#pragma unroll
    for (int v = 0; v < NLEV; ++v) {
        s[v] = gsum2[lane * 8 + v];
        c[v] = gcnt2[lane * 8 + v];
    }
#pragma unroll
    for (int v = 0; v < NLEV; ++v) {
#pragma unroll
        for (int off = 32; off > 0; off >>= 1) {
            s[v] += __shfl_xor(s[v], off, 64);
            c[v] += __shfl_xor(c[v], off, 64);
        }
    }
    if (lane == 0) {
        const float w[NLEV] = {1.f, 1.f / 2.f, 1.f / 3.f, 1.f / 4.f, 1.f / 5.f, 1.f / 6.f};
        float total = 0.f, lc = 0.f;
#pragma unroll
        for (int v = 0; v < NLEV; ++v) {
            const float cnt = (float)c[v];
            const float mse = s[v] / fmaxf(cnt, 1.f);
            const bool  use = c[v] >= 2u;
            total += use ? w[v] * mse : 0.f;
            lc    += use ? 1.f : 0.f;
        }
        out[0] = total / fmaxf(lc, 1.f);
    }
}

// ---------------------------------------------------------------------------
extern "C" void kernel_launch(void* const* d_in, const int* in_sizes, int n_in,
                              void* d_out, int out_size, void* d_ws, size_t ws_size,
                              hipStream_t stream)
{
    const float* z   = (const float*)d_in[0];
    const int*   idx = (const int*)d_in[1];
    char* ws = (char*)d_ws;
    u64*   zpk   = (u64*)(ws + WS_ZPK);
    float* sq    = (float*)(ws + WS_SQ);
    int*   rres  = (int*)(ws + WS_R);
    float* gsum2 = (float*)(ws + WS_ACC);
    u32*   gcnt2 = (u32*)(ws + WS_ACC + NSLOT * 8 * 4);
    float* out   = (float*)d_out;

    prep_kernel<<<N_ROWS / 4, 256, 0, stream>>>(z, idx, zpk, sq, rres, (u32*)gsum2);
    pair_kernel<<<NPAIR32, 64, 0, stream>>>(zpk, sq, rres, gsum2, gcnt2);
    finalize_kernel<<<1, 64, 0, stream>>>(gsum2, gcnt2, out);
}

// Round 18
// 48.364 us; speedup vs baseline: 1.2778x; 1.2778x over previous
//
#include <hip/hip_runtime.h>
#include <hip/hip_bf16.h>
#include <stdint.h>

typedef unsigned short u16;
typedef unsigned int   u32;
typedef unsigned long long u64;

#define N_ROWS 4096
#define DIM    512
#define NTI    128         // A tiles: 32 rows each
#define NTJ    64          // B tiles: 64 cols each
#define NPAIR  4160        // sum_{tj} (2*tj+2)  (= 8 * 520)
#define MOD3   729         // 3^6
#define NLEV   6           // levels v = 0..5
#define NKP    8           // k-pairs; each covers 64 k (two 16x16x32 steps)
#define NSLOT  64          // accumulator replication (de-contended atomics)

typedef __attribute__((ext_vector_type(2))) long  long2v;
typedef __attribute__((ext_vector_type(4))) float f32x4;

// ---- workspace layout (byte offsets) ----
// zpack: fp8 e4m3 SUPERBLOCKS (PROVEN R10-R15): superblock (R, kp) = 1 KB at
// ((R*8)+kp)*1024 covers 16-row group R, k-steps 2kp, 2kp+1; u64 slot L*2+h.
#define WS_ZPK 0
#define WS_SQ  (N_ROWS * DIM)
#define WS_R   (WS_SQ + N_ROWS * 4)
#define WS_ACC (WS_R + N_ROWS * 4)          // float gsum2[64][8]; u32 gcnt2[64][8]

// ---------------------------------------------------------------------------
// Prep (R10 verbatim, PROVEN): f32 -> fp8 pack into superblock zpack, row
// sum-of-squares, idx % 729; row 0 zeroes the 64-slot accumulators.
// ---------------------------------------------------------------------------
__global__ __launch_bounds__(256)
void prep_kernel(const float* __restrict__ z, const int* __restrict__ idx,
                 u64* __restrict__ zpack, float* __restrict__ sq,
                 int* __restrict__ rres, u32* __restrict__ acczero)
{
    const int lane = threadIdx.x & 63;
    const int row  = blockIdx.x * 4 + (threadIdx.x >> 6);
    const float4* zr = reinterpret_cast<const float4*>(z + (size_t)row * DIM) + lane * 2;
    float4 v0 = zr[0], v1 = zr[1];
    float f[8] = {v0.x, v0.y, v0.z, v0.w, v1.x, v1.y, v1.z, v1.w};
    float ss = 0.f;
#pragma unroll
    for (int k = 0; k < 8; ++k) ss += f[k] * f[k];
    int lo = __builtin_amdgcn_cvt_pk_fp8_f32(f[0], f[1], 0, false);
    lo     = __builtin_amdgcn_cvt_pk_fp8_f32(f[2], f[3], lo, true);
    int hi = __builtin_amdgcn_cvt_pk_fp8_f32(f[4], f[5], 0, false);
    hi     = __builtin_amdgcn_cvt_pk_fp8_f32(f[6], f[7], hi, true);
    const u64 pk = (u64)(u32)lo | ((u64)(u32)hi << 32);
    zpack[((size_t)((row >> 4) * 8 + (lane >> 3)) << 7)
          + ((lane & 3) * 16 + (row & 15)) * 2 + ((lane >> 2) & 1)] = pk;
#pragma unroll
    for (int off = 32; off > 0; off >>= 1) ss += __shfl_down(ss, off, 64);
    if (lane == 0) {
        sq[row] = ss;
        rres[row] = idx[row] % MOD3;   // idx >= 0
    }
    if (row == 0) {
#pragma unroll
        for (int i = 0; i < 16; ++i) acczero[lane + i * 64] = 0u;
    }
}

// ---------------------------------------------------------------------------
// Epilogue (R10 math verbatim, PROVEN absmax 0; 2x4 fragment grid, 32
// pairs/lane; DIAG compares GLOBAL indices since tiles are rectangular).
// ---------------------------------------------------------------------------
template<bool DIAG>
__device__ __forceinline__ void epilogue_acc(
    const f32x4 (&acc)[2][4], const float* sqI, const float* sqJ,
    const int* rI, const int* rJ, int I0, int J0, int lane,
    float (&lsum)[NLEV], u64& pcnt)
{
    const int rbase = (lane >> 4) * 4;   // C/D: row=(lane>>4)*4+q, col=lane&15
    const int cbase = lane & 15;
#pragma unroll
    for (int m = 0; m < 2; ++m) {
        const int il0 = m * 16 + rbase;
#pragma unroll
        for (int n = 0; n < 4; ++n) {
            const int jl  = n * 16 + cbase;
            const float sqj = sqJ[jl];
            const int   rj  = rJ[jl];
#pragma unroll
            for (int q = 0; q < 4; ++q) {
                const int il = il0 + q;
                float d2 = fmaxf(sqI[il] + sqj - 2.0f * acc[m][n][q], 0.f);
                const float dist = __builtin_amdgcn_sqrtf(d2);
                int dm = rI[il] - rj;
                dm += (dm >> 31) & MOD3;            // mod 729 into [0,729)
                const u32 x = (u32)dm;
                int v =
                    (x * 2863311531u <= 1431655765u) +   // 3
                    (x *  954437177u <=  477218588u) +   // 9
                    (x * 1749801491u <=  159072862u) +   // 27
                    (x * 2014922929u <=   53024287u) +   // 81
                    (x * 3534952507u <=   17674762u) +   // 243
                    (x * 4041629033u <=    5891587u);    // 729 (x==0 -> 6)
                if (DIAG) {
                    v = ((J0 + jl) > (I0 + il)) ? v : 6;
                }
                float tv = 1.0f;
                tv = (v == 1) ? (1.f / 3.f)   : tv;
                tv = (v == 2) ? (1.f / 9.f)   : tv;
                tv = (v == 3) ? (1.f / 27.f)  : tv;
                tv = (v == 4) ? (1.f / 81.f)  : tv;
                tv = (v == 5) ? (1.f / 243.f) : tv;
                const float dd  = dist - tv;
                const float sqd = dd * dd;
#pragma unroll
                for (int vv = 0; vv < NLEV; ++vv)
                    lsum[vv] += (v == vv) ? sqd : 0.f;
                pcnt += 1ull << (8 * v);            // 8-bit field per class (<=32)
            }
        }
    }
}

// ---------------------------------------------------------------------------
// Main: ONE WAVE per block, one 32x64 tile pair. Grid 4160 (2x R10's waves)
// with R10's PROVEN glds+counted-vmcnt pipeline at 12.8 KB LDS (cap 12
// blocks/CU vs R10's 9). Tile (ti, tj): A rows [32ti,32ti+32), B cols
// [64tj,64tj+64); pairs exist iff ti <= 2tj+1; DIAG (global i<j check)
// iff ti >= 2tj (A range inside B range). Aux staged by PLAIN loads fenced
// before the asm vmcnt queue (R12's 12-glds mistake avoided); epilogue is
// R10's register-only inline (R12's LUT-scatter mistake avoided).
// ---------------------------------------------------------------------------
__global__ __launch_bounds__(64, 4)
void pair_kernel(const u64* __restrict__ zpack, const float* __restrict__ sq,
                 const int* __restrict__ rres, float* __restrict__ gsum2,
                 u32* __restrict__ gcnt2)
{
    __shared__ __align__(16) u64 sb[2][6][128];   // 12 KB: 2 bufs x (2A + 4B)
    __shared__ float sqI[32], sqJ[64];
    __shared__ int   rI[32], rJ[64];

    const int lane = threadIdx.x;

    // bijective XCD swizzle (4160 = 8 * 520)
    const int wg = (blockIdx.x & 7) * (NPAIR / 8) + (blockIdx.x >> 3);
    // decode: tj blocks have (2*tj + 2) ti-slots
    int t = wg, tj = 0, rem = 2;
    while (t >= rem) { t -= rem; ++tj; rem += 2; }
    const int ti = t;
    const int I0 = ti * 32, J0 = tj * 64;
    const bool diag = (ti >= 2 * tj);

    // aux staging: plain loads + LDS writes, fenced BEFORE the glds queue.
    sqJ[lane] = sq[J0 + lane];
    rJ[lane]  = rres[J0 + lane];
    if (lane < 32) {
        sqI[lane] = sq[I0 + lane];
        rI[lane]  = rres[I0 + lane];
    }
    __builtin_amdgcn_sched_barrier(0);

    const int RA = 2 * ti, RB = 4 * tj;   // 16-row group bases

    // stage one k-pair: 6 superblocks (2 A + 4 B), one width-16 glds each.
#define STAGE(buf, kp)                                                         \
    {                                                                          \
        _Pragma("unroll")                                                      \
        for (int g = 0; g < 2; ++g)                                            \
            __builtin_amdgcn_global_load_lds(                                  \
                (const __attribute__((address_space(1))) u32*)                 \
                    (zpack + (((size_t)(RA + g) * 8 + (kp)) << 7) + lane * 2), \
                (__attribute__((address_space(3))) u32*)&sb[buf][g][0],        \
                16, 0, 0);                                                     \
        _Pragma("unroll")                                                      \
        for (int g = 0; g < 4; ++g)                                            \
            __builtin_amdgcn_global_load_lds(                                  \
                (const __attribute__((address_space(1))) u32*)                 \
                    (zpack + (((size_t)(RB + g) * 8 + (kp)) << 7) + lane * 2), \
                (__attribute__((address_space(3))) u32*)&sb[buf][2 + g][0],    \
                16, 0, 0);                                                     \
    }

    f32x4 acc[2][4];
#pragma unroll
    for (int m = 0; m < 2; ++m)
#pragma unroll
        for (int n = 0; n < 4; ++n) acc[m][n] = (f32x4){0.f, 0.f, 0.f, 0.f};

    STAGE(0, 0);
#pragma unroll
    for (int kp = 0; kp < NKP; ++kp) {
        const int buf = kp & 1;
        if (kp + 1 < NKP) {
            STAGE(buf ^ 1, kp + 1);
            // kp=0: queue = 6(kp0)+6(kp1) (aux used plain loads, already
            // drained by compiler waits) -> vmcnt(6) retires kp0, leaves kp1.
            asm volatile("s_waitcnt vmcnt(6)" ::: "memory");
        } else {
            asm volatile("s_waitcnt vmcnt(0)" ::: "memory");
        }
        __builtin_amdgcn_sched_barrier(0);
        long2v A2[2], B2[4];
#pragma unroll
        for (int g = 0; g < 2; ++g)
            A2[g] = reinterpret_cast<const long2v*>(&sb[buf][g][0])[lane];
#pragma unroll
        for (int g = 0; g < 4; ++g)
            B2[g] = reinterpret_cast<const long2v*>(&sb[buf][2 + g][0])[lane];
#pragma unroll
        for (int h = 0; h < 2; ++h)
#pragma unroll
            for (int m = 0; m < 2; ++m)
#pragma unroll
                for (int n = 0; n < 4; ++n)
                    acc[m][n] = __builtin_amdgcn_mfma_f32_16x16x32_fp8_fp8(
                        A2[m][h], B2[n][h], acc[m][n], 0, 0, 0);
    }
#undef STAGE

    // ---- fused epilogue (1 wave: no barriers anywhere) ----
    float lsum[NLEV] = {0.f, 0.f, 0.f, 0.f, 0.f, 0.f};
    u64 pcnt = 0ull;
    if (diag) epilogue_acc<true >(acc, sqI, sqJ, rI, rJ, I0, J0, lane, lsum, pcnt);
    else      epilogue_acc<false>(acc, sqI, sqJ, rI, rJ, I0, J0, lane, lsum, pcnt);

    // wave shuffle reduce, then atomics into slot (blockIdx & 63)
    const int slot = (int)(blockIdx.x & (NSLOT - 1));
#pragma unroll
    for (int vv = 0; vv < NLEV; ++vv) {
        float s = lsum[vv];
        u32   c = (u32)((pcnt >> (8 * vv)) & 255ull);
#pragma unroll
        for (int off = 32; off > 0; off >>= 1) {
            s += __shfl_xor(s, off, 64);
            c += __shfl_xor(c, off, 64);
        }
        if (lane == 0) {
            atomicAdd(&gsum2[slot * 8 + vv], s);
            atomicAdd(&gcnt2[slot * 8 + vv], c);
        }
    }
}

// ---------------------------------------------------------------------------
// Finalize (verbatim): lane t owns slot t; shuffle-reduce the 64 slots.
// ---------------------------------------------------------------------------
__global__ __launch_bounds__(64)
void finalize_kernel(const float* __restrict__ gsum2,
                     const u32* __restrict__ gcnt2,
                     float* __restrict__ out)
{
    const int lane = threadIdx.x;
    float s[NLEV];
    u32   c[NLEV];
#pragma unroll
    for (int v = 0; v < NLEV; ++v) {
        s[v] = gsum2[lane * 8 + v];
        c[v] = gcnt2[lane * 8 + v];
    }
#pragma unroll
    for (int v = 0; v < NLEV; ++v) {
#pragma unroll
        for (int off = 32; off > 0; off >>= 1) {
            s[v] += __shfl_xor(s[v], off, 64);
            c[v] += __shfl_xor(c[v], off, 64);
        }
    }
    if (lane == 0) {
        const float w[NLEV] = {1.f, 1.f / 2.f, 1.f / 3.f, 1.f / 4.f, 1.f / 5.f, 1.f / 6.f};
        float total = 0.f, lc = 0.f;
#pragma unroll
        for (int v = 0; v < NLEV; ++v) {
            const float cnt = (float)c[v];
            const float mse = s[v] / fmaxf(cnt, 1.f);
            const bool  use = c[v] >= 2u;
            total += use ? w[v] * mse : 0.f;
            lc    += use ? 1.f : 0.f;
        }
        out[0] = total / fmaxf(lc, 1.f);
    }
}

// ---------------------------------------------------------------------------
extern "C" void kernel_launch(void* const* d_in, const int* in_sizes, int n_in,
                              void* d_out, int out_size, void* d_ws, size_t ws_size,
                              hipStream_t stream)
{
    const float* z   = (const float*)d_in[0];
    const int*   idx = (const int*)d_in[1];
    char* ws = (char*)d_ws;
    u64*   zpk   = (u64*)(ws + WS_ZPK);
    float* sq    = (float*)(ws + WS_SQ);
    int*   rres  = (int*)(ws + WS_R);
    float* gsum2 = (float*)(ws + WS_ACC);
    u32*   gcnt2 = (u32*)(ws + WS_ACC + NSLOT * 8 * 4);
    float* out   = (float*)d_out;

    prep_kernel<<<N_ROWS / 4, 256, 0, stream>>>(z, idx, zpk, sq, rres, (u32*)gsum2);
    pair_kernel<<<NPAIR, 64, 0, stream>>>(zpk, sq, rres, gsum2, gcnt2);
    finalize_kernel<<<1, 64, 0, stream>>>(gsum2, gcnt2, out);
}